// Round 6
// baseline (316.629 us; speedup 1.0000x reference)
//
#include <hip/hip_runtime.h>
#include <cstdint>

typedef __attribute__((ext_vector_type(8))) short short8;
typedef __attribute__((ext_vector_type(4))) float floatx4;

__device__ __forceinline__ unsigned short f2bf(float f) {
  uint32_t u = __builtin_bit_cast(uint32_t, f);
  u += 0x7fffu + ((u >> 16) & 1u);   // RNE
  return (unsigned short)(u >> 16);
}
// pack bf16(lo) | bf16(hi)<<16, round-half-up: 2 adds + 1 v_perm
__device__ __forceinline__ uint32_t pkbf(float lo, float hi) {
  uint32_t a = __builtin_bit_cast(uint32_t, lo) + 0x8000u;
  uint32_t b = __builtin_bit_cast(uint32_t, hi) + 0x8000u;
  return __builtin_amdgcn_perm(b, a, 0x07060302);  // bytes: a[3:2] -> lo16, b[3:2] -> hi16
}

// ---------------- kernel 1: W transpose + convert (fp32 -> bf16) ----------------
__global__ void prep_w_kernel(const float* __restrict__ Wq,
                              const float* __restrict__ Wk,
                              const float* __restrict__ Wv,
                              unsigned short* __restrict__ Wt) {
  int idx = blockIdx.x * 256 + threadIdx.x;
  if (idx >= 576 * 768) return;
  int n = idx / 768;
  int k = idx - n * 768;
  int which = n / 192;
  int nn = n - which * 192;
  const float* W = (which == 0) ? Wq : (which == 1) ? Wk : Wv;
  Wt[idx] = f2bf(W[k * 192 + nn]);
}

// ---------------- kernel 2: QKV projection + RoPE (dbuf pipeline) ----------------
// grid (256 m-tiles, 3 which). Tile: 128 rows x 192 cols, BK=32, double-buffered LDS,
// ONE barrier per K-step; next tile's global loads issued before the barrier.
__global__ __launch_bounds__(256) void proj_kernel(
    const float* __restrict__ x, const unsigned short* __restrict__ Wt_all,
    unsigned short* __restrict__ q_ws, unsigned short* __restrict__ k_ws,
    unsigned short* __restrict__ v_ws) {
  // rows padded to 40 shorts (80 B) -> b128 frag reads are 2-way max (free, m136)
  __shared__ __align__(16) unsigned short A_lds[2][128 * 40];
  __shared__ __align__(16) unsigned short B_lds[2][192 * 40];
  const int tid = threadIdx.x;
  const int w = tid >> 6, l = tid & 63, quad = l >> 4, ln = l & 15;
  const int m0 = blockIdx.x * 128;
  const int which = blockIdx.y;
  const unsigned short* Wt = Wt_all + which * 192 * 768;

  // per-thread staging coords (constant; 'it' adds row strides)
  const int arow = tid >> 3, ac4 = tid & 7;  // A: +32 rows per it
  const int brow = tid >> 2, bc = tid & 3;   // B: +64 rows per it

  floatx4 acc[2][12];
#pragma unroll
  for (int mt = 0; mt < 2; ++mt)
#pragma unroll
    for (int nt = 0; nt < 12; ++nt) acc[mt][nt] = floatx4{0.f, 0.f, 0.f, 0.f};

  float4 fa[4];
  uint4 fb[3];
  // prologue: load kb=0, write buf0
#pragma unroll
  for (int it = 0; it < 4; ++it)
    fa[it] = *(const float4*)(x + (size_t)(m0 + arow + it * 32) * 768 + ac4 * 4);
#pragma unroll
  for (int it = 0; it < 3; ++it)
    fb[it] = *(const uint4*)(Wt + (brow + it * 64) * 768 + bc * 8);
#pragma unroll
  for (int it = 0; it < 4; ++it) {
    uint2 p = {pkbf(fa[it].x, fa[it].y), pkbf(fa[it].z, fa[it].w)};
    *(uint2*)&A_lds[0][(arow + it * 32) * 40 + ac4 * 4] = p;
  }
#pragma unroll
  for (int it = 0; it < 3; ++it)
    *(uint4*)&B_lds[0][(brow + it * 64) * 40 + bc * 8] = fb[it];

  for (int kb = 0; kb < 24; ++kb) {
    const int cur = kb & 1;
    // issue next tile's global loads BEFORE the barrier (fly across MFMA)
    if (kb < 23) {
      const int k1 = (kb + 1) * 32;
#pragma unroll
      for (int it = 0; it < 4; ++it)
        fa[it] = *(const float4*)(x + (size_t)(m0 + arow + it * 32) * 768 + k1 + ac4 * 4);
#pragma unroll
      for (int it = 0; it < 3; ++it)
        fb[it] = *(const uint4*)(Wt + (brow + it * 64) * 768 + k1 + bc * 8);
    }
    __syncthreads();  // buf[cur] writes visible; buf[cur^1] frag-reads (iter kb-1) done
    short8 a0 = *(const short8*)&A_lds[cur][(w * 32 + ln) * 40 + quad * 8];
    short8 a1 = *(const short8*)&A_lds[cur][(w * 32 + 16 + ln) * 40 + quad * 8];
#pragma unroll
    for (int nt = 0; nt < 12; ++nt) {
      short8 bfr = *(const short8*)&B_lds[cur][(nt * 16 + ln) * 40 + quad * 8];
      acc[0][nt] = __builtin_amdgcn_mfma_f32_16x16x32_bf16(a0, bfr, acc[0][nt], 0, 0, 0);
      acc[1][nt] = __builtin_amdgcn_mfma_f32_16x16x32_bf16(a1, bfr, acc[1][nt], 0, 0, 0);
    }
    if (kb < 23) {
      const int nxt = cur ^ 1;
#pragma unroll
      for (int it = 0; it < 4; ++it) {
        uint2 p = {pkbf(fa[it].x, fa[it].y), pkbf(fa[it].z, fa[it].w)};
        *(uint2*)&A_lds[nxt][(arow + it * 32) * 40 + ac4 * 4] = p;
      }
#pragma unroll
      for (int it = 0; it < 3; ++it)
        *(uint4*)&B_lds[nxt][(brow + it * 64) * 40 + bc * 8] = fb[it];
    }
  }

  // epilogue: RoPE on cols 0..31 for Q/K; V stored transposed [b][dim][t] (packed x4)
  if (which == 2) {
#pragma unroll
    for (int mt = 0; mt < 2; ++mt) {
      int rb = m0 + w * 32 + mt * 16 + quad * 4;  // 4 consecutive rows, same batch
      int bb = rb >> 9, t = rb & 511;
#pragma unroll
      for (int nt = 0; nt < 12; ++nt) {
        ushort4 pv;
        pv.x = f2bf(acc[mt][nt][0]); pv.y = f2bf(acc[mt][nt][1]);
        pv.z = f2bf(acc[mt][nt][2]); pv.w = f2bf(acc[mt][nt][3]);
        *(ushort4*)&v_ws[((size_t)bb * 192 + nt * 16 + ln) * 512 + t] = pv;
      }
    }
  } else {
    unsigned short* dst = (which == 0) ? q_ws : k_ws;
#pragma unroll
    for (int mt = 0; mt < 2; ++mt) {
#pragma unroll
      for (int r = 0; r < 4; ++r) {
        int row_g = m0 + w * 32 + mt * 16 + quad * 4 + r;
        int t_pos = row_g & 511;
        float vals[12];
#pragma unroll
        for (int nt = 0; nt < 12; ++nt) vals[nt] = acc[mt][nt][r];
#pragma unroll
        for (int nt = 0; nt < 2; ++nt) {
          int col = nt * 16 + ln;
          float v = vals[nt];
          float pv = __shfl_xor(v, 1);
          int i = col >> 1;
          float inv_freq = exp2f(-(float)i * (13.287712379549449f / 16.0f));
          float ang = (float)t_pos * inv_freq;
          float sv, cv;
          sincosf(ang, &sv, &cv);
          vals[nt] = (col & 1) ? (v * cv + pv * sv) : (v * cv - pv * sv);
        }
#pragma unroll
        for (int nt = 0; nt < 12; ++nt)
          dst[row_g * 192 + nt * 16 + ln] = f2bf(vals[nt]);
      }
    }
  }
}

// ---------------- kernel 3: causal flash attention (MFMA, prefetch + balance) ----------------
// grid (8, 64). qt remapped so dispatch-id i and i+256 carry complementary qt
// (every CU pair sums to 9 K-tiles instead of worst-case 16).
__global__ __launch_bounds__(256) void attn_kernel(
    const unsigned short* __restrict__ q_ws, const unsigned short* __restrict__ k_ws,
    const unsigned short* __restrict__ v_ws, float* __restrict__ out) {
  __shared__ __align__(16) unsigned short K_lds[64 * 200];
  __shared__ __align__(16) unsigned short V_lds[192 * 72];   // V^T: [dim][key]
  __shared__ __align__(16) unsigned short P_lds[4][16 * 72]; // per-wave P
  const int tid = threadIdx.x;
  const int w = tid >> 6, l = tid & 63, quad = l >> 4, ln = l & 15;
  const int b = blockIdx.y;
  const int qt = (blockIdx.y < 32) ? blockIdx.x : 7 - blockIdx.x;
  const int q0 = qt * 64;

  // staging coords (constant per thread)
  int krow[6], kcol[6];
#pragma unroll
  for (int it = 0; it < 6; ++it) {
    int idx = it * 256 + tid;
    krow[it] = idx / 24;
    kcol[it] = idx - krow[it] * 24;
  }
  const int vrow = tid >> 3, vcol = tid & 7;  // +32 rows per it

  // preload Q A-fragments
  short8 qf[6];
  {
    const unsigned short* qp =
        q_ws + (size_t)(b * 512 + q0 + w * 16 + ln) * 192 + quad * 8;
#pragma unroll
    for (int kk = 0; kk < 6; ++kk) qf[kk] = *(const short8*)(qp + kk * 32);
  }

  float m_i[4], l_i[4];
  floatx4 o[12];
#pragma unroll
  for (int r = 0; r < 4; ++r) { m_i[r] = -1e30f; l_i[r] = 0.f; }
#pragma unroll
  for (int nt = 0; nt < 12; ++nt) o[nt] = floatx4{0.f, 0.f, 0.f, 0.f};
  const float sm_scale = 0.07216878364870323f;  // 192^-0.5

  // prologue: load K/V tile 0 into registers
  uint4 kreg[6], vreg[6];
#pragma unroll
  for (int it = 0; it < 6; ++it)
    kreg[it] = *(const uint4*)(k_ws + (size_t)(b * 512 + krow[it]) * 192 + kcol[it] * 8);
#pragma unroll
  for (int it = 0; it < 6; ++it)
    vreg[it] = *(const uint4*)(v_ws + (size_t)(b * 192 + vrow + it * 32) * 512 + vcol * 8);

  for (int kt = 0; kt <= qt; ++kt) {
    __syncthreads();  // previous tile's LDS frag reads done
#pragma unroll
    for (int it = 0; it < 6; ++it)
      *(uint4*)&K_lds[krow[it] * 200 + kcol[it] * 8] = kreg[it];
#pragma unroll
    for (int it = 0; it < 6; ++it)
      *(uint4*)&V_lds[(vrow + it * 32) * 72 + vcol * 8] = vreg[it];
    if (kt < qt) {  // prefetch next tile; loads fly across the whole compute phase
      const int k1 = (kt + 1) * 64;
#pragma unroll
      for (int it = 0; it < 6; ++it)
        kreg[it] = *(const uint4*)(k_ws + (size_t)(b * 512 + k1 + krow[it]) * 192 + kcol[it] * 8);
#pragma unroll
      for (int it = 0; it < 6; ++it)
        vreg[it] = *(const uint4*)(v_ws + (size_t)(b * 192 + vrow + it * 32) * 512 + k1 + vcol * 8);
    }
    __syncthreads();  // staging visible

    // S = Q K^T (scaled)
    float s[4][4];
#pragma unroll
    for (int nt = 0; nt < 4; ++nt) {
      floatx4 sa = floatx4{0.f, 0.f, 0.f, 0.f};
#pragma unroll
      for (int kk = 0; kk < 6; ++kk) {
        short8 kf = *(const short8*)&K_lds[(nt * 16 + ln) * 200 + kk * 32 + quad * 8];
        sa = __builtin_amdgcn_mfma_f32_16x16x32_bf16(qf[kk], kf, sa, 0, 0, 0);
      }
#pragma unroll
      for (int r = 0; r < 4; ++r) s[nt][r] = sa[r] * sm_scale;
    }
    if (kt == qt) {  // diagonal tile mask (k0 == q0)
#pragma unroll
      for (int nt = 0; nt < 4; ++nt)
#pragma unroll
        for (int r = 0; r < 4; ++r)
          if (nt * 16 + ln > w * 16 + quad * 4 + r) s[nt][r] = -1e30f;
    }
    // online softmax (row = quad*4+r)
    float alpha[4];
#pragma unroll
    for (int r = 0; r < 4; ++r) {
      float mx = fmaxf(fmaxf(s[0][r], s[1][r]), fmaxf(s[2][r], s[3][r]));
      mx = fmaxf(mx, __shfl_xor(mx, 1));
      mx = fmaxf(mx, __shfl_xor(mx, 2));
      mx = fmaxf(mx, __shfl_xor(mx, 4));
      mx = fmaxf(mx, __shfl_xor(mx, 8));
      float mnew = fmaxf(m_i[r], mx);
      alpha[r] = __expf(m_i[r] - mnew);
      float sum = 0.f;
#pragma unroll
      for (int nt = 0; nt < 4; ++nt) {
        s[nt][r] = __expf(s[nt][r] - mnew);
        sum += s[nt][r];
      }
      sum += __shfl_xor(sum, 1);
      sum += __shfl_xor(sum, 2);
      sum += __shfl_xor(sum, 4);
      sum += __shfl_xor(sum, 8);
      l_i[r] = l_i[r] * alpha[r] + sum;
      m_i[r] = mnew;
    }
#pragma unroll
    for (int nt = 0; nt < 12; ++nt)
#pragma unroll
      for (int r = 0; r < 4; ++r) o[nt][r] *= alpha[r];

    // P: C/D layout -> A layout via per-wave LDS
#pragma unroll
    for (int nt = 0; nt < 4; ++nt)
#pragma unroll
      for (int r = 0; r < 4; ++r)
        P_lds[w][(quad * 4 + r) * 72 + nt * 16 + ln] = f2bf(s[nt][r]);
    __asm__ volatile("s_waitcnt lgkmcnt(0)" ::: "memory");  // wave-local write->read

    // O += P V
#pragma unroll
    for (int ks = 0; ks < 2; ++ks) {
      short8 pf = *(const short8*)&P_lds[w][ln * 72 + ks * 32 + quad * 8];
#pragma unroll
      for (int nt = 0; nt < 12; ++nt) {
        short8 vf = *(const short8*)&V_lds[(nt * 16 + ln) * 72 + ks * 32 + quad * 8];
        o[nt] = __builtin_amdgcn_mfma_f32_16x16x32_bf16(pf, vf, o[nt], 0, 0, 0);
      }
    }
  }

  // epilogue: O/l -> fp32 out [b][t][dim]
#pragma unroll
  for (int r = 0; r < 4; ++r) {
    float inv = 1.0f / l_i[r];
    size_t rowoff = (size_t)(b * 512 + q0 + w * 16 + quad * 4 + r) * 192;
#pragma unroll
    for (int nt = 0; nt < 12; ++nt)
      out[rowoff + nt * 16 + ln] = o[nt][r] * inv;
  }
}

extern "C" void kernel_launch(void* const* d_in, const int* in_sizes, int n_in,
                              void* d_out, int out_size, void* d_ws, size_t ws_size,
                              hipStream_t stream) {
  const float* x = (const float*)d_in[0];
  const float* Wq = (const float*)d_in[1];
  const float* Wk = (const float*)d_in[2];
  const float* Wv = (const float*)d_in[3];
  float* out = (float*)d_out;

  char* ws = (char*)d_ws;
  const size_t QKV_BYTES = (size_t)64 * 512 * 192 * 2;  // 12,582,912
  unsigned short* q_ws = (unsigned short*)(ws);
  unsigned short* k_ws = (unsigned short*)(ws + QKV_BYTES);
  unsigned short* v_ws = (unsigned short*)(ws + 2 * QKV_BYTES);
  unsigned short* Wt = (unsigned short*)(ws + 3 * QKV_BYTES);

  hipLaunchKernelGGL(prep_w_kernel, dim3(1728), dim3(256), 0, stream, Wq, Wk, Wv, Wt);
  hipLaunchKernelGGL(proj_kernel, dim3(256, 3), dim3(256), 0, stream, x, Wt, q_ws, k_ws, v_ws);
  hipLaunchKernelGGL(attn_kernel, dim3(8, 64), dim3(256), 0, stream, q_ws, k_ws, v_ws, out);
}

// Round 7
// 241.423 us; speedup vs baseline: 1.3115x; 1.3115x over previous
//
#include <hip/hip_runtime.h>
#include <cstdint>

typedef __attribute__((ext_vector_type(8))) short short8;
typedef __attribute__((ext_vector_type(4))) float floatx4;

__device__ __forceinline__ unsigned short f2bf(float f) {
  uint32_t u = __builtin_bit_cast(uint32_t, f);
  u += 0x7fffu + ((u >> 16) & 1u);   // RNE
  return (unsigned short)(u >> 16);
}
// pack bf16(lo)|bf16(hi)<<16, round-half-up: 2 adds + 1 v_perm
__device__ __forceinline__ uint32_t pkbf(float lo, float hi) {
  uint32_t a = __builtin_bit_cast(uint32_t, lo) + 0x8000u;
  uint32_t b = __builtin_bit_cast(uint32_t, hi) + 0x8000u;
  return __builtin_amdgcn_perm(b, a, 0x07060302);
}

// ---------------- kernel 1: W transpose + convert (fp32 -> bf16) ----------------
__global__ void prep_w_kernel(const float* __restrict__ Wq,
                              const float* __restrict__ Wk,
                              const float* __restrict__ Wv,
                              unsigned short* __restrict__ Wt) {
  int idx = blockIdx.x * 256 + threadIdx.x;
  if (idx >= 576 * 768) return;
  int n = idx / 768;
  int k = idx - n * 768;
  int which = n / 192;
  int nn = n - which * 192;
  const float* W = (which == 0) ? Wq : (which == 1) ? Wk : Wv;
  Wt[idx] = f2bf(W[k * 192 + nn]);
}

// ---------------- kernel 2: QKV projection + RoPE ----------------
// grid (512 m-tiles, 3 which). Tile: 64 rows x 192 cols, BK=32.
// Wave w: rows w*16..w*16+15, 12 ntiles -> 48 AGPR acc. Low footprint => 4-6 blocks/CU
// resident; cross-block overlap hides the 2-barrier drain (m114).
__global__ __launch_bounds__(256) void proj_kernel(
    const float* __restrict__ x, const unsigned short* __restrict__ Wt_all,
    unsigned short* __restrict__ q_ws, unsigned short* __restrict__ k_ws,
    unsigned short* __restrict__ v_ws) {
  // rows padded to 40 shorts (80 B) -> b128 frag reads 2-way max (free, m136)
  __shared__ __align__(16) unsigned short A_lds[64 * 40];
  __shared__ __align__(16) unsigned short B_lds[192 * 40];
  const int tid = threadIdx.x;
  const int w = tid >> 6, l = tid & 63, quad = l >> 4, ln = l & 15;
  const int m0 = blockIdx.x * 64;
  const int which = blockIdx.y;
  const unsigned short* Wt = Wt_all + which * 192 * 768;

  const int arow = tid >> 3, ac4 = tid & 7;  // A: +32 rows on it=1
  const int brow = tid >> 2, bc = tid & 3;   // B: +64 rows per it

  floatx4 acc[12];
#pragma unroll
  for (int nt = 0; nt < 12; ++nt) acc[nt] = floatx4{0.f, 0.f, 0.f, 0.f};

  for (int kb = 0; kb < 24; ++kb) {
    const int k0 = kb * 32;
    // stage A: x[m0..m0+63][k0..k0+31] fp32 -> bf16 (2 float4/thread)
#pragma unroll
    for (int it = 0; it < 2; ++it) {
      float4 f = *(const float4*)(x + (size_t)(m0 + arow + it * 32) * 768 + k0 + ac4 * 4);
      uint2 p = {pkbf(f.x, f.y), pkbf(f.z, f.w)};
      *(uint2*)&A_lds[(arow + it * 32) * 40 + ac4 * 4] = p;
    }
    // stage B: Wt[0..191][k0..k0+31] (3 uint4/thread)
#pragma unroll
    for (int it = 0; it < 3; ++it) {
      uint4 v = *(const uint4*)(Wt + (brow + it * 64) * 768 + k0 + bc * 8);
      *(uint4*)&B_lds[(brow + it * 64) * 40 + bc * 8] = v;
    }
    __syncthreads();
    short8 a0 = *(const short8*)&A_lds[(w * 16 + ln) * 40 + quad * 8];
#pragma unroll
    for (int nt = 0; nt < 12; ++nt) {
      short8 bfr = *(const short8*)&B_lds[(nt * 16 + ln) * 40 + quad * 8];
      acc[nt] = __builtin_amdgcn_mfma_f32_16x16x32_bf16(a0, bfr, acc[nt], 0, 0, 0);
    }
    __syncthreads();
  }

  // epilogue: RoPE on cols 0..31 for Q/K; V stored transposed [b][dim][t]
  if (which == 2) {
    int rb = m0 + w * 16 + quad * 4;  // 4 consecutive rows, same batch (64 | 512)
    int bb = rb >> 9, t = rb & 511;
#pragma unroll
    for (int nt = 0; nt < 12; ++nt) {
      ushort4 pv;
      pv.x = f2bf(acc[nt][0]); pv.y = f2bf(acc[nt][1]);
      pv.z = f2bf(acc[nt][2]); pv.w = f2bf(acc[nt][3]);
      *(ushort4*)&v_ws[((size_t)bb * 192 + nt * 16 + ln) * 512 + t] = pv;
    }
  } else {
    unsigned short* dst = (which == 0) ? q_ws : k_ws;
#pragma unroll
    for (int r = 0; r < 4; ++r) {
      int row_g = m0 + w * 16 + quad * 4 + r;
      int t_pos = row_g & 511;
      float vals[12];
#pragma unroll
      for (int nt = 0; nt < 12; ++nt) vals[nt] = acc[nt][r];
#pragma unroll
      for (int nt = 0; nt < 2; ++nt) {
        int col = nt * 16 + ln;
        float v = vals[nt];
        float pv = __shfl_xor(v, 1);
        int i = col >> 1;
        float inv_freq = exp2f(-(float)i * (13.287712379549449f / 16.0f));
        float ang = (float)t_pos * inv_freq;
        float sv, cv;
        sincosf(ang, &sv, &cv);
        vals[nt] = (col & 1) ? (v * cv + pv * sv) : (v * cv - pv * sv);
      }
#pragma unroll
      for (int nt = 0; nt < 12; ++nt)
        dst[row_g * 192 + nt * 16 + ln] = f2bf(vals[nt]);
    }
  }
}

// ---------------- kernel 3: causal flash attention (MFMA) ----------------
// grid (8, 64). qt remap: dispatch i and i+256 carry complementary qt
// (CU pair sums to 9 K-tiles, was worst-case 16). No register prefetch (VGPR trap).
__global__ __launch_bounds__(256) void attn_kernel(
    const unsigned short* __restrict__ q_ws, const unsigned short* __restrict__ k_ws,
    const unsigned short* __restrict__ v_ws, float* __restrict__ out) {
  __shared__ __align__(16) unsigned short K_lds[64 * 200];
  __shared__ __align__(16) unsigned short V_lds[192 * 72];   // V^T: [dim][key]
  __shared__ __align__(16) unsigned short P_lds[4][16 * 72]; // per-wave P
  const int tid = threadIdx.x;
  const int w = tid >> 6, l = tid & 63, quad = l >> 4, ln = l & 15;
  const int b = blockIdx.y;
  const int qt = (blockIdx.y < 32) ? blockIdx.x : 7 - blockIdx.x;
  const int q0 = qt * 64;

  // preload Q A-fragments
  short8 qf[6];
  {
    const unsigned short* qp =
        q_ws + (size_t)(b * 512 + q0 + w * 16 + ln) * 192 + quad * 8;
#pragma unroll
    for (int kk = 0; kk < 6; ++kk) qf[kk] = *(const short8*)(qp + kk * 32);
  }

  float m_i[4], l_i[4];
  floatx4 o[12];
#pragma unroll
  for (int r = 0; r < 4; ++r) { m_i[r] = -1e30f; l_i[r] = 0.f; }
#pragma unroll
  for (int nt = 0; nt < 12; ++nt) o[nt] = floatx4{0.f, 0.f, 0.f, 0.f};
  const float sm_scale = 0.07216878364870323f;  // 192^-0.5

  for (int kt = 0; kt <= qt; ++kt) {
    const int k0 = kt * 64;
    __syncthreads();  // previous iteration's LDS reads done before overwrite
    // stage K tile [64][192]
#pragma unroll
    for (int it = 0; it < 6; ++it) {
      int idx = it * 256 + tid;
      int row = idx / 24, c = idx - row * 24;
      uint4 v = *(const uint4*)(k_ws + (size_t)(b * 512 + k0 + row) * 192 + c * 8);
      *(uint4*)&K_lds[row * 200 + c * 8] = v;
    }
    // stage V^T tile [192][64]
#pragma unroll
    for (int it = 0; it < 6; ++it) {
      int idx = it * 256 + tid;
      int row = idx >> 3, c = idx & 7;
      uint4 v = *(const uint4*)(v_ws + (size_t)(b * 192 + row) * 512 + k0 + c * 8);
      *(uint4*)&V_lds[row * 72 + c * 8] = v;
    }
    __syncthreads();

    // S = Q K^T (scaled)
    float s[4][4];
#pragma unroll
    for (int nt = 0; nt < 4; ++nt) {
      floatx4 sa = floatx4{0.f, 0.f, 0.f, 0.f};
#pragma unroll
      for (int kk = 0; kk < 6; ++kk) {
        short8 kf = *(const short8*)&K_lds[(nt * 16 + ln) * 200 + kk * 32 + quad * 8];
        sa = __builtin_amdgcn_mfma_f32_16x16x32_bf16(qf[kk], kf, sa, 0, 0, 0);
      }
#pragma unroll
      for (int r = 0; r < 4; ++r) s[nt][r] = sa[r] * sm_scale;
    }
    if (kt == qt) {  // diagonal tile mask (k0 == q0)
#pragma unroll
      for (int nt = 0; nt < 4; ++nt)
#pragma unroll
        for (int r = 0; r < 4; ++r)
          if (nt * 16 + ln > w * 16 + quad * 4 + r) s[nt][r] = -1e30f;
    }
    // online softmax (row = quad*4+r)
    float alpha[4];
#pragma unroll
    for (int r = 0; r < 4; ++r) {
      float mx = fmaxf(fmaxf(s[0][r], s[1][r]), fmaxf(s[2][r], s[3][r]));
      mx = fmaxf(mx, __shfl_xor(mx, 1));
      mx = fmaxf(mx, __shfl_xor(mx, 2));
      mx = fmaxf(mx, __shfl_xor(mx, 4));
      mx = fmaxf(mx, __shfl_xor(mx, 8));
      float mnew = fmaxf(m_i[r], mx);
      alpha[r] = __expf(m_i[r] - mnew);
      float sum = 0.f;
#pragma unroll
      for (int nt = 0; nt < 4; ++nt) {
        s[nt][r] = __expf(s[nt][r] - mnew);
        sum += s[nt][r];
      }
      sum += __shfl_xor(sum, 1);
      sum += __shfl_xor(sum, 2);
      sum += __shfl_xor(sum, 4);
      sum += __shfl_xor(sum, 8);
      l_i[r] = l_i[r] * alpha[r] + sum;
      m_i[r] = mnew;
    }
#pragma unroll
    for (int nt = 0; nt < 12; ++nt)
#pragma unroll
      for (int r = 0; r < 4; ++r) o[nt][r] *= alpha[r];

    // P: C/D layout -> A layout via per-wave LDS
#pragma unroll
    for (int nt = 0; nt < 4; ++nt)
#pragma unroll
      for (int r = 0; r < 4; ++r)
        P_lds[w][(quad * 4 + r) * 72 + nt * 16 + ln] = f2bf(s[nt][r]);
    __asm__ volatile("s_waitcnt lgkmcnt(0)" ::: "memory");  // wave-local write->read

    // O += P V
#pragma unroll
    for (int ks = 0; ks < 2; ++ks) {
      short8 pf = *(const short8*)&P_lds[w][ln * 72 + ks * 32 + quad * 8];
#pragma unroll
      for (int nt = 0; nt < 12; ++nt) {
        short8 vf = *(const short8*)&V_lds[(nt * 16 + ln) * 72 + ks * 32 + quad * 8];
        o[nt] = __builtin_amdgcn_mfma_f32_16x16x32_bf16(pf, vf, o[nt], 0, 0, 0);
      }
    }
  }

  // epilogue: O/l -> fp32 out [b][t][dim]
#pragma unroll
  for (int r = 0; r < 4; ++r) {
    float inv = 1.0f / l_i[r];
    size_t rowoff = (size_t)(b * 512 + q0 + w * 16 + quad * 4 + r) * 192;
#pragma unroll
    for (int nt = 0; nt < 12; ++nt)
      out[rowoff + nt * 16 + ln] = o[nt][r] * inv;
  }
}

extern "C" void kernel_launch(void* const* d_in, const int* in_sizes, int n_in,
                              void* d_out, int out_size, void* d_ws, size_t ws_size,
                              hipStream_t stream) {
  const float* x = (const float*)d_in[0];
  const float* Wq = (const float*)d_in[1];
  const float* Wk = (const float*)d_in[2];
  const float* Wv = (const float*)d_in[3];
  float* out = (float*)d_out;

  char* ws = (char*)d_ws;
  const size_t QKV_BYTES = (size_t)64 * 512 * 192 * 2;  // 12,582,912
  unsigned short* q_ws = (unsigned short*)(ws);
  unsigned short* k_ws = (unsigned short*)(ws + QKV_BYTES);
  unsigned short* v_ws = (unsigned short*)(ws + 2 * QKV_BYTES);
  unsigned short* Wt = (unsigned short*)(ws + 3 * QKV_BYTES);

  hipLaunchKernelGGL(prep_w_kernel, dim3(1728), dim3(256), 0, stream, Wq, Wk, Wv, Wt);
  hipLaunchKernelGGL(proj_kernel, dim3(512, 3), dim3(256), 0, stream, x, Wt, q_ws, k_ws, v_ws);
  hipLaunchKernelGGL(attn_kernel, dim3(8, 64), dim3(256), 0, stream, q_ws, k_ws, v_ws, out);
}